// Round 6
// baseline (474.760 us; speedup 1.0000x reference)
//
#include <hip/hip_runtime.h>

#define NN 50000     // nodes
#define NE 200000    // edges
#define DF 364       // feature dim
#define KP 384       // padded K (12 x 32)
#define DOUT 150     // output dim
#define NP 8192      // pairs
#define NEG_SLOPE 0.01f

typedef float f32x4 __attribute__((ext_vector_type(4)));
typedef short bf16x8 __attribute__((ext_vector_type(8)));

__device__ __forceinline__ unsigned short f2bf(float x) {
    unsigned u = __float_as_uint(x);
    u += 0x7FFF + ((u >> 16) & 1);  // RN-even; inputs finite
    return (unsigned short)(u >> 16);
}
__device__ __forceinline__ float bf2f(unsigned short h) {
    return __uint_as_float(((unsigned)h) << 16);
}

__device__ __forceinline__ void mfma16(f32x4& d, bf16x8 a, bf16x8 b) {
    d = __builtin_amdgcn_mfma_f32_16x16x32_bf16(a, b, d, 0, 0, 0);
}

// FRAG layout (both A-by-rows and B-by-cols), validated against round-5's
// hardware-verified fragment mapping (row=lane&15, k=(lane>>4)*8+e):
//   g = row>>4, rr = row&15, c = k>>5, sub = (k>>3)&3, e = k&7
//   flat = (g*12 + c)*512 + sub*128 + rr*8 + e
// A wave's fragment (16 rows x k-chunk c) = contiguous 1 KB at (g*12+c)*512 + lane*8.

// ---------------- CSR build ----------------

__global__ void hist_kernel(const int* __restrict__ dst, int* __restrict__ deg, int n) {
    int t = blockIdx.x * blockDim.x + threadIdx.x;
    if (t < n) atomicAdd(&deg[dst[t]], 1);
}

__global__ __launch_bounds__(1024) void scan_block(const int* __restrict__ deg,
                                                   int* __restrict__ rowptr,
                                                   int* __restrict__ bsum, int n) {
    __shared__ int lds[1024];
    int b = blockIdx.x, t = threadIdx.x;
    int i = b * 1024 + t;
    int v = (i < n) ? deg[i] : 0;
    lds[t] = v;
    __syncthreads();
    for (int off = 1; off < 1024; off <<= 1) {
        int x = (t >= off) ? lds[t - off] : 0;
        __syncthreads();
        lds[t] += x;
        __syncthreads();
    }
    if (i < n) rowptr[i] = lds[t] - v;
    if (t == 1023) bsum[b] = lds[1023];
}

__global__ void scan_small(int* __restrict__ bsum, int nb) {
    int t = threadIdx.x;
    int orig = (t < nb) ? bsum[t] : 0;
    int v = orig;
#pragma unroll
    for (int off = 1; off < 64; off <<= 1) {
        int u = __shfl_up(v, off, 64);
        if (t >= off) v += u;
    }
    if (t < nb) bsum[t] = v - orig;
}

__global__ __launch_bounds__(1024) void add_off(int* __restrict__ rowptr,
                                                const int* __restrict__ bsum,
                                                int* __restrict__ pos, int n) {
    int i = blockIdx.x * 1024 + threadIdx.x;
    if (i < n) {
        int v = rowptr[i] + bsum[blockIdx.x];
        rowptr[i] = v;
        pos[i] = v;
    }
}

__global__ void fill_kernel(const int* __restrict__ src, const int* __restrict__ dst,
                            int* __restrict__ pos, int* __restrict__ esrc, int n) {
    int t = blockIdx.x * blockDim.x + threadIdx.x;
    if (t < n) {
        int j = atomicAdd(&pos[dst[t]], 1);
        esrc[j] = src[t];
    }
}

// ---------------- split-plane helpers ----------------

__device__ __forceinline__ void split4(float4 v, ushort4& h, ushort4& l) {
    h.x = f2bf(v.x); l.x = f2bf(v.x - bf2f(h.x));
    h.y = f2bf(v.y); l.y = f2bf(v.y - bf2f(h.y));
    h.z = f2bf(v.z); l.z = f2bf(v.z - bf2f(h.z));
    h.w = f2bf(v.w); l.w = f2bf(v.w - bf2f(h.w));
}

__device__ __forceinline__ float4 load4(const ushort* ih, const ushort* il, size_t off) {
    ushort4 h = *(const ushort4*)&ih[off];
    ushort4 l = *(const ushort4*)&il[off];
    return make_float4(bf2f(h.x) + bf2f(l.x), bf2f(h.y) + bf2f(l.y),
                       bf2f(h.z) + bf2f(l.z), bf2f(h.w) + bf2f(l.w));
}

__device__ __forceinline__ void f4add(float4& a, const float4 b) {
    a.x += b.x; a.y += b.y; a.z += b.z; a.w += b.w;
}

// frag-layout ushort4 store offset for lane-chunk i of the LOW 256 k (k0 = 4i)
__device__ __forceinline__ size_t frag_off_lo(int g, int rr, int i) {
    return (size_t)(g * 12 + (i >> 3)) * 512 + ((i >> 1) & 3) * 128 + rr * 8 + (i & 1) * 4;
}
// and for the HIGH 128 k (k0 = 256 + 4i), i in 0..31
__device__ __forceinline__ size_t frag_off_hi(int g, int rr, int i) {
    return (size_t)(g * 12 + 8 + (i >> 3)) * 512 + ((i >> 1) & 3) * 128 + rr * 8 + (i & 1) * 4;
}

// ---------------- agg1: fp32 features -> FRAG split planes ----------------
// one wave per row; lane i holds k 4i..4i+3 (a0) and k 256+4i.. (a1, lanes<27)

__global__ __launch_bounds__(256) void agg1_kernel(
    const float* __restrict__ x, const int* __restrict__ rowptr,
    const int* __restrict__ deg, const int* __restrict__ esrc,
    ushort* __restrict__ oh, ushort* __restrict__ ol, int nrows) {
    int wid = (blockIdx.x * 256 + threadIdx.x) >> 6;
    if (wid >= nrows) return;
    int lane = threadIdx.x & 63;
    int start = rowptr[wid];
    int d = deg[wid];
    bool hi2 = lane < 27;

    const float4* xr = reinterpret_cast<const float4*>(x + (size_t)wid * DF);
    float4 a0 = xr[lane];
    float4 a1 = hi2 ? xr[64 + lane] : make_float4(0.f, 0.f, 0.f, 0.f);

    int j = 0;
    for (; j + 1 < d; j += 2) {
        int s0 = esrc[start + j], s1 = esrc[start + j + 1];
        const float4* r0 = reinterpret_cast<const float4*>(x + (size_t)s0 * DF);
        const float4* r1 = reinterpret_cast<const float4*>(x + (size_t)s1 * DF);
        float4 b0 = r0[lane], b1 = r1[lane];
        f4add(a0, b0);
        f4add(a0, b1);
        if (hi2) {
            float4 c0 = r0[64 + lane], c1 = r1[64 + lane];
            f4add(a1, c0);
            f4add(a1, c1);
        }
    }
    if (j < d) {
        int s0 = esrc[start + j];
        const float4* r0 = reinterpret_cast<const float4*>(x + (size_t)s0 * DF);
        f4add(a0, r0[lane]);
        if (hi2) f4add(a1, r0[64 + lane]);
    }

    int g = wid >> 4, rr = wid & 15;
    ushort4 h, l;
    split4(a0, h, l);
    size_t o0 = frag_off_lo(g, rr, lane);
    *(ushort4*)&oh[o0] = h;
    *(ushort4*)&ol[o0] = l;
    if (lane < 32) {  // k 256..383; lanes 27..31 are zero-pad (k >= 364)
        float4 v = hi2 ? a1 : make_float4(0.f, 0.f, 0.f, 0.f);
        split4(v, h, l);
        size_t o1 = frag_off_hi(g, rr, lane);
        *(ushort4*)&oh[o1] = h;
        *(ushort4*)&ol[o1] = l;
    }
}

// ---------------- agg2: row-major split planes -> FRAG split planes, gathered ----------------

__global__ __launch_bounds__(256) void agg2_kernel(
    const ushort* __restrict__ ih, const ushort* __restrict__ il,
    const int* __restrict__ rowptr, const int* __restrict__ deg,
    const int* __restrict__ esrc, const int* __restrict__ v1,
    const int* __restrict__ v2,
    ushort* __restrict__ oh, ushort* __restrict__ ol, int nrows) {
    int wid = (blockIdx.x * 256 + threadIdx.x) >> 6;
    if (wid >= nrows) return;
    int lane = threadIdx.x & 63;
    int node = (wid < NP) ? v1[wid] : v2[wid - NP];
    int start = rowptr[node];
    int d = deg[node];
    bool hi2 = lane < 27;

    size_t nb = (size_t)node * KP;
    float4 a0 = load4(ih, il, nb + 4 * lane);
    float4 a1 = hi2 ? load4(ih, il, nb + 256 + 4 * lane) : make_float4(0.f, 0.f, 0.f, 0.f);

    for (int j = 0; j < d; ++j) {
        int s = esrc[start + j];
        size_t sb = (size_t)s * KP;
        f4add(a0, load4(ih, il, sb + 4 * lane));
        if (hi2) f4add(a1, load4(ih, il, sb + 256 + 4 * lane));
    }

    int g = wid >> 4, rr = wid & 15;
    ushort4 h, l;
    split4(a0, h, l);
    size_t o0 = frag_off_lo(g, rr, lane);
    *(ushort4*)&oh[o0] = h;
    *(ushort4*)&ol[o0] = l;
    if (lane < 32) {
        float4 v = hi2 ? a1 : make_float4(0.f, 0.f, 0.f, 0.f);
        split4(v, h, l);
        size_t o1 = frag_off_hi(g, rr, lane);
        *(ushort4*)&oh[o1] = h;
        *(ushort4*)&ol[o1] = l;
    }
}

// ---------------- weight prep: W[K][N] fp32 -> FRAG hi/lo planes over (n, k) ----------------

__global__ void prep_w(const float* __restrict__ W, int K, int Nn,
                       ushort* __restrict__ th, ushort* __restrict__ tl) {
    int idx = blockIdx.x * 256 + threadIdx.x;
    if (idx >= KP * KP) return;
    int e = idx & 7;
    int rr = (idx >> 3) & 15;
    int sub = (idx >> 7) & 3;
    int gc = idx >> 9;
    int g = gc / 12, c = gc - g * 12;
    int k = c * 32 + sub * 8 + e;
    int n = g * 16 + rr;
    float v = (k < K && n < Nn) ? W[(size_t)k * Nn + n] : 0.f;
    unsigned short h = f2bf(v);
    th[idx] = h;
    tl[idx] = f2bf(v - bf2f(h));
}

// ---------------- no-LDS MFMA GEMM: one wave = one 64x64 tile ----------------
// A, B in FRAG layout; per K-step: 16 contiguous 1KB loads + 48 MFMA, no barriers.
// Split-bf16: acc += ah*bh + ah*bl + al*bh.
// mode 0: C -> row-major hi/lo planes (stride KP, pad cols zeroed)
// mode 1: C -> FRAG hi/lo planes
// mode 2: C -> fp32 row-major (stride Nn)

__global__ __launch_bounds__(256) void gemm_frag(
    const ushort* __restrict__ Ahi, const ushort* __restrict__ Alo,
    const ushort* __restrict__ Bh, const ushort* __restrict__ Bl,
    const float* __restrict__ bias,
    ushort* __restrict__ Chi, ushort* __restrict__ Clo, float* __restrict__ Cf32,
    int M, int Nn, int nrt, int nct, int mode) {
    int wv = threadIdx.x >> 6;
    int lane = threadIdx.x & 63;
    int gwid = blockIdx.x * 4 + wv;
    if (gwid >= nrt * nct) return;
    int rt = gwid / nct, ct = gwid - rt * nct;

    const ushort* pAh = Ahi + (size_t)rt * 4 * 12 * 512 + lane * 8;
    const ushort* pAl = Alo + (size_t)rt * 4 * 12 * 512 + lane * 8;
    const ushort* pBh = Bh + (size_t)ct * 4 * 12 * 512 + lane * 8;
    const ushort* pBl = Bl + (size_t)ct * 4 * 12 * 512 + lane * 8;

    f32x4 acc[4][4];
#pragma unroll
    for (int m = 0; m < 4; ++m)
#pragma unroll
        for (int n = 0; n < 4; ++n) acc[m][n] = (f32x4){0.f, 0.f, 0.f, 0.f};

    for (int t = 0; t < KP / 32; ++t) {
        bf16x8 ah[4], al[4], bh[4], bl[4];
#pragma unroll
        for (int m = 0; m < 4; ++m) {
            ah[m] = *(const bf16x8*)(pAh + (m * 12 + t) * 512);
            al[m] = *(const bf16x8*)(pAl + (m * 12 + t) * 512);
        }
#pragma unroll
        for (int n = 0; n < 4; ++n) {
            bh[n] = *(const bf16x8*)(pBh + (n * 12 + t) * 512);
            bl[n] = *(const bf16x8*)(pBl + (n * 12 + t) * 512);
        }
#pragma unroll
        for (int m = 0; m < 4; ++m)
#pragma unroll
            for (int n = 0; n < 4; ++n) {
                mfma16(acc[m][n], ah[m], bh[n]);
                mfma16(acc[m][n], ah[m], bl[n]);
                mfma16(acc[m][n], al[m], bh[n]);
            }
    }

    // epilogue: C/D layout col=lane&15, row=(lane>>4)*4+reg  [m89-verified]
    int crow_l = (lane >> 4) * 4;
    int ccol_l = lane & 15;
#pragma unroll
    for (int n = 0; n < 4; ++n) {
        int col = ct * 64 + n * 16 + ccol_l;
        bool cok = (col < Nn);
        float bn = cok ? bias[col] : 0.f;
#pragma unroll
        for (int m = 0; m < 4; ++m) {
#pragma unroll
            for (int r = 0; r < 4; ++r) {
                int row = rt * 64 + m * 16 + crow_l + r;
                if (row >= M) continue;
                float v = acc[m][n][r] + bn;
                v = (v >= 0.f) ? v : NEG_SLOPE * v;
                if (mode == 2) {
                    if (cok) Cf32[(size_t)row * Nn + col] = v;
                } else {
                    unsigned short h = 0, l = 0;
                    if (cok) {
                        h = f2bf(v);
                        l = f2bf(v - bf2f(h));
                    }
                    size_t off;
                    if (mode == 0) {
                        off = (size_t)row * KP + col;
                    } else {
                        off = (size_t)((row >> 4) * 12 + (col >> 5)) * 512 +
                              ((col >> 3) & 3) * 128 + (row & 15) * 8 + (col & 7);
                    }
                    Chi[off] = h;
                    Clo[off] = l;
                }
            }
        }
    }
}

// ---------------- row L2 normalize (in place) ----------------

__global__ __launch_bounds__(256) void norm_kernel(float* __restrict__ out, int nrows) {
    int wid = (blockIdx.x * 256 + threadIdx.x) >> 6;
    if (wid >= nrows) return;
    int lane = threadIdx.x & 63;
    float* row = out + (size_t)wid * DOUT;
    float a = row[lane];
    float b = row[lane + 64];
    float cc = (lane + 128 < DOUT) ? row[lane + 128] : 0.f;
    float s = a * a + b * b + cc * cc;
#pragma unroll
    for (int off = 32; off; off >>= 1) s += __shfl_xor(s, off, 64);
    float scale = 1.0f / fmaxf(sqrtf(s), 1e-12f);
    row[lane] = a * scale;
    row[lane + 64] = b * scale;
    if (lane + 128 < DOUT) row[lane + 128] = cc * scale;
}

// ---------------- launch ----------------

extern "C" void kernel_launch(void* const* d_in, const int* in_sizes, int n_in,
                              void* d_out, int out_size, void* d_ws, size_t ws_size,
                              hipStream_t stream) {
    const float* features = (const float*)d_in[0];
    const int* src = (const int*)d_in[1];
    const int* dst = (const int*)d_in[2];
    const int* v1 = (const int*)d_in[3];
    const int* v2 = (const int*)d_in[4];
    const float* W1 = (const float*)d_in[5];
    const float* b1 = (const float*)d_in[6];
    const float* W2 = (const float*)d_in[7];
    const float* b2 = (const float*)d_in[8];
    const float* W3 = (const float*)d_in[9];
    const float* b3 = (const float*)d_in[10];
    float* out = (float*)d_out;

    const int MPAD = 50048;                  // 782 row-tiles * 64 = 3128 groups * 16
    const size_t PLANE = (size_t)MPAD * KP;  // ushort elems (same for frag & row layouts)
    const size_t WSZ = (size_t)KP * KP;

    char* p = (char*)d_ws;
    ushort* a1h = (ushort*)p; p += PLANE * 2;   // frag
    ushort* a1l = (ushort*)p; p += PLANE * 2;
    ushort* h1h = (ushort*)p; p += PLANE * 2;   // row-major planes
    ushort* h1l = (ushort*)p; p += PLANE * 2;
    ushort* wt1h = (ushort*)p; p += WSZ * 2;
    ushort* wt1l = (ushort*)p; p += WSZ * 2;
    ushort* wt2h = (ushort*)p; p += WSZ * 2;
    ushort* wt2l = (ushort*)p; p += WSZ * 2;
    ushort* wt3h = (ushort*)p; p += WSZ * 2;
    ushort* wt3l = (ushort*)p; p += WSZ * 2;
    int* deg = (int*)p; p += NN * 4;
    int* rowptr = (int*)p; p += NN * 4;
    int* pos = (int*)p; p += NN * 4;
    int* esrc = (int*)p; p += NE * 4;
    int* bsum = (int*)p; p += 256;
    // reuse after consumers finish:
    ushort* a2h = a1h;  // layer-2 agg out (frag, 16384 rows) reuses a1
    ushort* a2l = a1l;
    ushort* h2h = h1h;  // layer-2 gemm out (frag) reuses h1
    ushort* h2l = h1l;

    const int NSB = (NN + 1023) / 1024;

    hipMemsetAsync(deg, 0, NN * sizeof(int), stream);
    hist_kernel<<<(NE + 255) / 256, 256, 0, stream>>>(dst, deg, NE);
    scan_block<<<NSB, 1024, 0, stream>>>(deg, rowptr, bsum, NN);
    scan_small<<<1, 64, 0, stream>>>(bsum, NSB);
    add_off<<<NSB, 1024, 0, stream>>>(rowptr, bsum, pos, NN);
    fill_kernel<<<(NE + 255) / 256, 256, 0, stream>>>(src, dst, pos, esrc, NE);

    prep_w<<<(KP * KP + 255) / 256, 256, 0, stream>>>(W1, DF, DF, wt1h, wt1l);
    prep_w<<<(KP * KP + 255) / 256, 256, 0, stream>>>(W2, DF, DF, wt2h, wt2l);
    prep_w<<<(KP * KP + 255) / 256, 256, 0, stream>>>(W3, DF, DOUT, wt3h, wt3l);

    // layer 1 (all nodes): A frag -> C row-planes
    agg1_kernel<<<(NN * 64 + 255) / 256, 256, 0, stream>>>(features, rowptr, deg, esrc,
                                                           a1h, a1l, NN);
    {
        int nrt = MPAD / 64, nct = 6;  // 782 x 6 waves
        gemm_frag<<<(nrt * nct + 3) / 4, 256, 0, stream>>>(
            a1h, a1l, wt1h, wt1l, b1, h1h, h1l, nullptr, NN, DF, nrt, nct, 0);
    }

    // layer 2 (16384 gathered rows): reads h1 row-planes, writes a2 frag
    const int NR = 2 * NP;
    agg2_kernel<<<(NR * 64 + 255) / 256, 256, 0, stream>>>(h1h, h1l, rowptr, deg, esrc,
                                                           v1, v2, a2h, a2l, NR);
    {
        int nrt = NR / 64, nct = 6;  // 256 x 6
        gemm_frag<<<(nrt * nct + 3) / 4, 256, 0, stream>>>(
            a2h, a2l, wt2h, wt2l, b2, h2h, h2l, nullptr, NR, DF, nrt, nct, 1);
    }

    // projection -> d_out (fp32), then in-place normalize
    {
        int nrt = NR / 64, nct = 3;  // 256 x 3 (cols 0..191 cover N=150)
        gemm_frag<<<(nrt * nct + 3) / 4, 256, 0, stream>>>(
            h2h, h2l, wt3h, wt3l, b3, nullptr, nullptr, out, NR, DOUT, nrt, nct, 2);
    }
    norm_kernel<<<(NR * 64 + 255) / 256, 256, 0, stream>>>(out, NR);
}

// Round 9
// 349.533 us; speedup vs baseline: 1.3583x; 1.3583x over previous
//
#include <hip/hip_runtime.h>

#define NN 50000     // nodes
#define NE 200000    // edges
#define DF 364       // feature dim
#define KP 384       // padded K (12 x 32)
#define DOUT 150     // output dim
#define NP 8192      // pairs
#define NEG_SLOPE 0.01f

typedef float f32x4 __attribute__((ext_vector_type(4)));
typedef short bf16x8 __attribute__((ext_vector_type(8)));
typedef unsigned short u16x8 __attribute__((ext_vector_type(8)));

__device__ __forceinline__ unsigned short f2bf(float x) {
    unsigned u = __float_as_uint(x);
    u += 0x7FFF + ((u >> 16) & 1);  // RN-even; inputs finite
    return (unsigned short)(u >> 16);
}
__device__ __forceinline__ float bf2f(unsigned short h) {
    return __uint_as_float(((unsigned)h) << 16);
}

__device__ __forceinline__ void mfma16(f32x4& d, bf16x8 a, bf16x8 b) {
    d = __builtin_amdgcn_mfma_f32_16x16x32_bf16(a, b, d, 0, 0, 0);
}

// FRAG layout (validated by round-6 pass): for (row, k):
//   g=row>>4, rr=row&15, c=k>>5, sub=(k>>3)&3, e=k&7
//   flat = (g*12 + c)*512 + sub*128 + rr*8 + e
// One 16-row x 32-k block = 512 contiguous elems = 1KB; lane's frag = 16B at lane*8.

// ---------------- CSR build ----------------

__global__ void hist_kernel(const int* __restrict__ dst, int* __restrict__ deg, int n) {
    int t = blockIdx.x * blockDim.x + threadIdx.x;
    if (t < n) atomicAdd(&deg[dst[t]], 1);
}

__global__ __launch_bounds__(1024) void scan_block(const int* __restrict__ deg,
                                                   int* __restrict__ rowptr,
                                                   int* __restrict__ bsum, int n) {
    __shared__ int lds[1024];
    int b = blockIdx.x, t = threadIdx.x;
    int i = b * 1024 + t;
    int v = (i < n) ? deg[i] : 0;
    lds[t] = v;
    __syncthreads();
    for (int off = 1; off < 1024; off <<= 1) {
        int x = (t >= off) ? lds[t - off] : 0;
        __syncthreads();
        lds[t] += x;
        __syncthreads();
    }
    if (i < n) rowptr[i] = lds[t] - v;
    if (t == 1023) bsum[b] = lds[1023];
}

__global__ void scan_small(int* __restrict__ bsum, int nb) {
    int t = threadIdx.x;
    int orig = (t < nb) ? bsum[t] : 0;
    int v = orig;
#pragma unroll
    for (int off = 1; off < 64; off <<= 1) {
        int u = __shfl_up(v, off, 64);
        if (t >= off) v += u;
    }
    if (t < nb) bsum[t] = v - orig;
}

__global__ __launch_bounds__(1024) void add_off(int* __restrict__ rowptr,
                                                const int* __restrict__ bsum,
                                                int* __restrict__ pos, int n) {
    int i = blockIdx.x * 1024 + threadIdx.x;
    if (i < n) {
        int v = rowptr[i] + bsum[blockIdx.x];
        rowptr[i] = v;
        pos[i] = v;
    }
}

__global__ void fill_kernel(const int* __restrict__ src, const int* __restrict__ dst,
                            int* __restrict__ pos, int* __restrict__ esrc, int n) {
    int t = blockIdx.x * blockDim.x + threadIdx.x;
    if (t < n) {
        int j = atomicAdd(&pos[dst[t]], 1);
        esrc[j] = src[t];
    }
}

// ---------------- helpers ----------------

__device__ __forceinline__ void f4add(float4& a, const float4 b) {
    a.x += b.x; a.y += b.y; a.z += b.z; a.w += b.w;
}

__device__ __forceinline__ ushort4 round4(float4 v) {
    ushort4 h;
    h.x = f2bf(v.x); h.y = f2bf(v.y); h.z = f2bf(v.z); h.w = f2bf(v.w);
    return h;
}

// frag ushort4 store offset for lane-chunk i, LOW 256 k (k0 = 4i), i in 0..63
__device__ __forceinline__ size_t frag_off_lo(int g, int rr, int i) {
    return (size_t)(g * 12 + (i >> 3)) * 512 + ((i >> 1) & 3) * 128 + rr * 8 + (i & 1) * 4;
}
// HIGH 128 k (k0 = 256 + 4i), i in 0..31
__device__ __forceinline__ size_t frag_off_hi(int g, int rr, int i) {
    return (size_t)(g * 12 + 8 + (i >> 3)) * 512 + ((i >> 1) & 3) * 128 + rr * 8 + (i & 1) * 4;
}

// ---------------- agg1: fp32 features -> FRAG bf16 plane ----------------
// one wave per node; lane i holds k 4i..4i+3 (a0) and k 256+4i.. (a1, lanes<27)

__global__ __launch_bounds__(256) void agg1_kernel(
    const float* __restrict__ x, const int* __restrict__ rowptr,
    const int* __restrict__ deg, const int* __restrict__ esrc,
    ushort* __restrict__ of, int nrows) {
    int wid = (blockIdx.x * 256 + threadIdx.x) >> 6;
    if (wid >= nrows) return;
    int lane = threadIdx.x & 63;
    int start = rowptr[wid];
    int d = deg[wid];
    bool hi2 = lane < 27;

    const float4* xr = reinterpret_cast<const float4*>(x + (size_t)wid * DF);
    float4 a0 = xr[lane];
    float4 a1 = hi2 ? xr[64 + lane] : make_float4(0.f, 0.f, 0.f, 0.f);

    int j = 0;
    for (; j + 1 < d; j += 2) {
        int s0 = esrc[start + j], s1 = esrc[start + j + 1];
        const float4* r0 = reinterpret_cast<const float4*>(x + (size_t)s0 * DF);
        const float4* r1 = reinterpret_cast<const float4*>(x + (size_t)s1 * DF);
        float4 b0 = r0[lane], b1 = r1[lane];
        f4add(a0, b0);
        f4add(a0, b1);
        if (hi2) {
            float4 c0 = r0[64 + lane], c1 = r1[64 + lane];
            f4add(a1, c0);
            f4add(a1, c1);
        }
    }
    if (j < d) {
        int s0 = esrc[start + j];
        const float4* r0 = reinterpret_cast<const float4*>(x + (size_t)s0 * DF);
        f4add(a0, r0[lane]);
        if (hi2) f4add(a1, r0[64 + lane]);
    }

    int g = wid >> 4, rr = wid & 15;
    *(ushort4*)&of[frag_off_lo(g, rr, lane)] = round4(a0);
    if (lane < 32) {  // k 256..383; lanes 27..31 zero-pad (k >= 364)
        float4 v = hi2 ? a1 : make_float4(0.f, 0.f, 0.f, 0.f);
        *(ushort4*)&of[frag_off_hi(g, rr, lane)] = round4(v);
    }
}

// ---------------- agg2: row-major bf16 h1 -> FRAG bf16, gathered rows ----------------
// one wave per output row; lanes 0..47 each own 8 consecutive k (k = lane*8)

__global__ __launch_bounds__(256) void agg2_kernel(
    const ushort* __restrict__ h1, const int* __restrict__ rowptr,
    const int* __restrict__ deg, const int* __restrict__ esrc,
    const int* __restrict__ v1, const int* __restrict__ v2,
    ushort* __restrict__ of, int nrows) {
    int wid = (blockIdx.x * 256 + threadIdx.x) >> 6;
    if (wid >= nrows) return;
    int lane = threadIdx.x & 63;
    int node = (wid < NP) ? v1[wid] : v2[wid - NP];
    int start = rowptr[node];
    int d = deg[node];
    bool act = lane < 48;  // 48 * 8 = 384 cols

    float f[8] = {};
    if (act) {
        u16x8 v = *(const u16x8*)&h1[(size_t)node * KP + lane * 8];
#pragma unroll
        for (int i = 0; i < 8; ++i) f[i] = bf2f(v[i]);
    }
    for (int j = 0; j < d; ++j) {
        int s = esrc[start + j];
        if (act) {
            u16x8 v = *(const u16x8*)&h1[(size_t)s * KP + lane * 8];
#pragma unroll
            for (int i = 0; i < 8; ++i) f[i] += bf2f(v[i]);
        }
    }
    if (act) {
        u16x8 o;
#pragma unroll
        for (int i = 0; i < 8; ++i) o[i] = f2bf(f[i]);
        int g = wid >> 4, rr = wid & 15;
        // k = lane*8: c = lane>>2, sub = lane&3, e = 0..7 contiguous
        size_t off = (size_t)(g * 12 + (lane >> 2)) * 512 + (lane & 3) * 128 + rr * 8;
        *(u16x8*)&of[off] = o;
    }
}

// ---------------- weight prep: W[K][N] fp32 -> FRAG hi/lo planes over (n, k) ----------------

__global__ void prep_w(const float* __restrict__ W, int K, int Nn,
                       ushort* __restrict__ th, ushort* __restrict__ tl) {
    int idx = blockIdx.x * 256 + threadIdx.x;
    if (idx >= KP * KP) return;
    int e = idx & 7;
    int rr = (idx >> 3) & 15;
    int sub = (idx >> 7) & 3;
    int gc = idx >> 9;
    int g = gc / 12, c = gc - g * 12;
    int k = c * 32 + sub * 8 + e;
    int n = g * 16 + rr;
    float v = (k < K && n < Nn) ? W[(size_t)k * Nn + n] : 0.f;
    unsigned short h = f2bf(v);
    th[idx] = h;
    tl[idx] = f2bf(v - bf2f(h));
}

// ---------------- LDS MFMA GEMM: C = lrelu(A @ B^T + bias) ----------------
// A frag bf16 [row][k]; B frag hi/lo [n][k]. 128x128 tile, 4 waves (2x2), 64x64 each.
// Numerics: acc += a*bh + a*bl  (A bf16, B split -> ~2^-10 rel error from A only).
// LDS: 2 bufs x 3 planes (A, Bh, Bl) x 4096 ushort = 48 KB -> 3 blocks/CU.
// Staging: 24 x 1KB linear global_load_lds per buffer (frag layout = linear), 6/wave.
// mode 0: C -> row-major bf16 (stride KP, pad cols zeroed)
// mode 1: C -> FRAG bf16
// mode 2: C -> fp32 row-major (stride Nn)

__global__ __launch_bounds__(256, 3) void gemm_lds(
    const ushort* __restrict__ Af, const ushort* __restrict__ Bhf,
    const ushort* __restrict__ Blf, const float* __restrict__ bias,
    ushort* __restrict__ Cbf, float* __restrict__ Cf32,
    int M, int Nn, int mode) {
    __shared__ __align__(16) ushort lds[2][3][4096];  // 48 KB

    int tid = threadIdx.x;
    int lane = tid & 63;
    int wv = tid >> 6;
    int wr = wv >> 1, wc = wv & 1;
    int brow = blockIdx.x * 128, bcol = blockIdx.y * 128;
    int rg = brow >> 4, cg = bcol >> 4;

#define STAGE(buf, tt)                                                                  \
    do {                                                                                \
        _Pragma("unroll") for (int j_ = 0; j_ < 6; ++j_) {                              \
            int g24_ = wv * 6 + j_;                                                     \
            int p_ = g24_ >> 3, gg_ = g24_ & 7;                                         \
            const ushort* base_ = (p_ == 0) ? Af : ((p_ == 1) ? Bhf : Blf);             \
            int grp_ = ((p_ == 0) ? rg : cg) + gg_;                                     \
            const ushort* s_ = base_ + ((size_t)grp_ * 12 + (tt)) * 512 + lane * 8;     \
            __builtin_amdgcn_global_load_lds(                                           \
                (const __attribute__((address_space(1))) unsigned int*)s_,              \
                (__attribute__((address_space(3))) unsigned int*)(&lds[buf][p_][gg_ * 512]), \
                16, 0, 0);                                                              \
        }                                                                               \
    } while (0)

    // fragment read offset within a plane: group*512 + sub*128 + rr*8
    int flo = (lane >> 4) * 128 + (lane & 15) * 8;

    f32x4 acc[4][4];
#pragma unroll
    for (int m = 0; m < 4; ++m)
#pragma unroll
        for (int n = 0; n < 4; ++n) acc[m][n] = (f32x4){0.f, 0.f, 0.f, 0.f};

    STAGE(0, 0);
    __syncthreads();

    for (int t = 0; t < KP / 32; ++t) {
        int cur = t & 1;
        if (t + 1 < KP / 32) STAGE(1 - cur, t + 1);
        bf16x8 a[4], bh[4], bl[4];
#pragma unroll
        for (int m = 0; m < 4; ++m)
            a[m] = *(const bf16x8*)&lds[cur][0][(wr * 4 + m) * 512 + flo];
#pragma unroll
        for (int n = 0; n < 4; ++n) {
            bh[n] = *(const bf16x8*)&lds[cur][1][(wc * 4 + n) * 512 + flo];
            bl[n] = *(const bf16x8*)&lds[cur][2][(wc * 4 + n) * 512 + flo];
        }
#pragma unroll
        for (int m = 0; m < 4; ++m)
#pragma unroll
            for (int n = 0; n < 4; ++n) {
                mfma16(acc[m][n], a[m], bh[n]);
                mfma16(acc[m][n], a[m], bl[n]);
            }
        __syncthreads();
    }
#undef STAGE

    // epilogue: C/D layout col=lane&15, row=(lane>>4)*4+reg  [hardware-validated]
    int crow_l = (lane >> 4) * 4;
    int ccol_l = lane & 15;
#pragma unroll
    for (int n = 0; n < 4; ++n) {
        int col = bcol + wc * 64 + n * 16 + ccol_l;
        bool cok = (col < Nn);
        float bn = cok ? bias[col] : 0.f;
#pragma unroll
        for (int m = 0; m < 4; ++m) {
#pragma unroll
            for (int r = 0; r < 4; ++r) {
                int row = brow + wr * 64 + m * 16 + crow_l + r;
                if (row >= M) continue;
                float v = acc[m][n][r] + bn;
                v = (v >= 0.f) ? v : NEG_SLOPE * v;
                if (mode == 2) {
                    if (cok) Cf32[(size_t)row * Nn + col] = v;
                } else {
                    unsigned short h = cok ? f2bf(v) : (unsigned short)0;
                    size_t off;
                    if (mode == 0) {
                        off = (size_t)row * KP + col;
                    } else {
                        off = (size_t)((row >> 4) * 12 + (col >> 5)) * 512 +
                              ((col >> 3) & 3) * 128 + (row & 15) * 8 + (col & 7);
                    }
                    Cbf[off] = h;
                }
            }
        }
    }
}

// ---------------- row L2 normalize (in place) ----------------

__global__ __launch_bounds__(256) void norm_kernel(float* __restrict__ out, int nrows) {
    int wid = (blockIdx.x * 256 + threadIdx.x) >> 6;
    if (wid >= nrows) return;
    int lane = threadIdx.x & 63;
    float* row = out + (size_t)wid * DOUT;
    float a = row[lane];
    float b = row[lane + 64];
    float cc = (lane + 128 < DOUT) ? row[lane + 128] : 0.f;
    float s = a * a + b * b + cc * cc;
#pragma unroll
    for (int off = 32; off; off >>= 1) s += __shfl_xor(s, off, 64);
    float scale = 1.0f / fmaxf(sqrtf(s), 1e-12f);
    row[lane] = a * scale;
    row[lane + 64] = b * scale;
    if (lane + 128 < DOUT) row[lane + 128] = cc * scale;
}

// ---------------- launch ----------------

extern "C" void kernel_launch(void* const* d_in, const int* in_sizes, int n_in,
                              void* d_out, int out_size, void* d_ws, size_t ws_size,
                              hipStream_t stream) {
    const float* features = (const float*)d_in[0];
    const int* src = (const int*)d_in[1];
    const int* dst = (const int*)d_in[2];
    const int* v1 = (const int*)d_in[3];
    const int* v2 = (const int*)d_in[4];
    const float* W1 = (const float*)d_in[5];
    const float* b1 = (const float*)d_in[6];
    const float* W2 = (const float*)d_in[7];
    const float* b2 = (const float*)d_in[8];
    const float* W3 = (const float*)d_in[9];
    const float* b3 = (const float*)d_in[10];
    float* out = (float*)d_out;

    const int MPAD = 50048;                  // 391 row-tiles of 128
    const size_t PLANE = (size_t)MPAD * KP;  // ushort elems
    const size_t WSZ = (size_t)KP * KP;

    char* p = (char*)d_ws;
    ushort* a1f = (ushort*)p; p += PLANE * 2;   // A frag bf16 (layer 1 / reused layer 2)
    ushort* h1 = (ushort*)p; p += PLANE * 2;    // h1 row-major bf16 / reused h2 frag
    ushort* wt1h = (ushort*)p; p += WSZ * 2;
    ushort* wt1l = (ushort*)p; p += WSZ * 2;
    ushort* wt2h = (ushort*)p; p += WSZ * 2;
    ushort* wt2l = (ushort*)p; p += WSZ * 2;
    ushort* wt3h = (ushort*)p; p += WSZ * 2;
    ushort* wt3l = (ushort*)p; p += WSZ * 2;
    int* deg = (int*)p; p += NN * 4;
    int* rowptr = (int*)p; p += NN * 4;
    int* pos = (int*)p; p += NN * 4;
    int* esrc = (int*)p; p += NE * 4;
    int* bsum = (int*)p; p += 256;
    ushort* a2f = a1f;  // layer-2 agg out (frag, 16384 rows)
    ushort* h2f = h1;   // layer-2 gemm out (frag)

    const int NSB = (NN + 1023) / 1024;

    hipMemsetAsync(deg, 0, NN * sizeof(int), stream);
    hist_kernel<<<(NE + 255) / 256, 256, 0, stream>>>(dst, deg, NE);
    scan_block<<<NSB, 1024, 0, stream>>>(deg, rowptr, bsum, NN);
    scan_small<<<1, 64, 0, stream>>>(bsum, NSB);
    add_off<<<NSB, 1024, 0, stream>>>(rowptr, bsum, pos, NN);
    fill_kernel<<<(NE + 255) / 256, 256, 0, stream>>>(src, dst, pos, esrc, NE);

    prep_w<<<(KP * KP + 255) / 256, 256, 0, stream>>>(W1, DF, DF, wt1h, wt1l);
    prep_w<<<(KP * KP + 255) / 256, 256, 0, stream>>>(W2, DF, DF, wt2h, wt2l);
    prep_w<<<(KP * KP + 255) / 256, 256, 0, stream>>>(W3, DF, DOUT, wt3h, wt3l);

    // layer 1 (all nodes): A frag -> h1 row-major bf16
    agg1_kernel<<<(NN * 64 + 255) / 256, 256, 0, stream>>>(features, rowptr, deg, esrc,
                                                           a1f, NN);
    gemm_lds<<<dim3(391, 3), 256, 0, stream>>>(a1f, wt1h, wt1l, b1,
                                               h1, nullptr, NN, DF, 0);

    // layer 2 (16384 gathered rows): h1 row-major -> a2 frag -> h2 frag
    const int NR = 2 * NP;
    agg2_kernel<<<(NR * 64 + 255) / 256, 256, 0, stream>>>(h1, rowptr, deg, esrc,
                                                           v1, v2, a2f, NR);
    gemm_lds<<<dim3(128, 3), 256, 0, stream>>>(a2f, wt2h, wt2l, b2,
                                               h2f, nullptr, NR, DF, 1);

    // projection -> d_out (fp32), then in-place normalize
    gemm_lds<<<dim3(128, 2), 256, 0, stream>>>(h2f, wt3h, wt3l, b3,
                                               nullptr, out, NR, DOUT, 2);
    norm_kernel<<<(NR * 64 + 255) / 256, 256, 0, stream>>>(out, NR);
}

// Round 10
// 302.739 us; speedup vs baseline: 1.5682x; 1.1546x over previous
//
#include <hip/hip_runtime.h>

#define NN 50000     // nodes
#define NE 200000    // edges
#define DF 364       // feature dim
#define KP 384       // padded K (12 x 32)
#define DOUT 150     // output dim
#define NP 8192      // pairs
#define NEG_SLOPE 0.01f

typedef float f32x4 __attribute__((ext_vector_type(4)));
typedef short bf16x8 __attribute__((ext_vector_type(8)));
typedef unsigned short u16x8 __attribute__((ext_vector_type(8)));

__device__ __forceinline__ unsigned short f2bf(float x) {
    unsigned u = __float_as_uint(x);
    u += 0x7FFF + ((u >> 16) & 1);  // RN-even; inputs finite
    return (unsigned short)(u >> 16);
}
__device__ __forceinline__ float bf2f(unsigned short h) {
    return __uint_as_float(((unsigned)h) << 16);
}

__device__ __forceinline__ void mfma16(f32x4& d, bf16x8 a, bf16x8 b) {
    d = __builtin_amdgcn_mfma_f32_16x16x32_bf16(a, b, d, 0, 0, 0);
}

// FRAG layout (hardware-validated rounds 6/9): for (idx, k):
//   g=idx>>4, rr=idx&15, c=k>>5, sub=(k>>3)&3, e=k&7
//   flat = (g*12 + c)*512 + sub*128 + rr*8 + e
// Symmetric for A-by-rows and B-by-cols (same function), so swapping operand
// roles is purely a pointer/grid change.

// ---------------- CSR build ----------------

__global__ void hist_kernel(const int* __restrict__ dst, int* __restrict__ deg, int n) {
    int t = blockIdx.x * blockDim.x + threadIdx.x;
    if (t < n) atomicAdd(&deg[dst[t]], 1);
}

__global__ __launch_bounds__(1024) void scan_block(const int* __restrict__ deg,
                                                   int* __restrict__ rowptr,
                                                   int* __restrict__ bsum, int n) {
    __shared__ int lds[1024];
    int b = blockIdx.x, t = threadIdx.x;
    int i = b * 1024 + t;
    int v = (i < n) ? deg[i] : 0;
    lds[t] = v;
    __syncthreads();
    for (int off = 1; off < 1024; off <<= 1) {
        int x = (t >= off) ? lds[t - off] : 0;
        __syncthreads();
        lds[t] += x;
        __syncthreads();
    }
    if (i < n) rowptr[i] = lds[t] - v;
    if (t == 1023) bsum[b] = lds[1023];
}

__global__ void scan_small(int* __restrict__ bsum, int nb) {
    int t = threadIdx.x;
    int orig = (t < nb) ? bsum[t] : 0;
    int v = orig;
#pragma unroll
    for (int off = 1; off < 64; off <<= 1) {
        int u = __shfl_up(v, off, 64);
        if (t >= off) v += u;
    }
    if (t < nb) bsum[t] = v - orig;
}

__global__ __launch_bounds__(1024) void add_off(int* __restrict__ rowptr,
                                                const int* __restrict__ bsum,
                                                int* __restrict__ pos, int n) {
    int i = blockIdx.x * 1024 + threadIdx.x;
    if (i < n) {
        int v = rowptr[i] + bsum[blockIdx.x];
        rowptr[i] = v;
        pos[i] = v;
    }
}

__global__ void fill_kernel(const int* __restrict__ src, const int* __restrict__ dst,
                            int* __restrict__ pos, int* __restrict__ esrc, int n) {
    int t = blockIdx.x * blockDim.x + threadIdx.x;
    if (t < n) {
        int j = atomicAdd(&pos[dst[t]], 1);
        esrc[j] = src[t];
    }
}

// ---------------- helpers ----------------

__device__ __forceinline__ ushort4 round4(float4 v) {
    ushort4 h;
    h.x = f2bf(v.x); h.y = f2bf(v.y); h.z = f2bf(v.z); h.w = f2bf(v.w);
    return h;
}

__device__ __forceinline__ float4 bf4tof4(ushort4 u) {
    return make_float4(bf2f(u.x), bf2f(u.y), bf2f(u.z), bf2f(u.w));
}

__device__ __forceinline__ void f4add(float4& a, const float4 b) {
    a.x += b.x; a.y += b.y; a.z += b.z; a.w += b.w;
}

// frag ushort4 store offset for lane-chunk i, LOW 256 k (k0 = 4i), i in 0..63
__device__ __forceinline__ size_t frag_off_lo(int g, int rr, int i) {
    return (size_t)(g * 12 + (i >> 3)) * 512 + ((i >> 1) & 3) * 128 + rr * 8 + (i & 1) * 4;
}
// HIGH 128 k (k0 = 256 + 4i), i in 0..31
__device__ __forceinline__ size_t frag_off_hi(int g, int rr, int i) {
    return (size_t)(g * 12 + 8 + (i >> 3)) * 512 + ((i >> 1) & 3) * 128 + rr * 8 + (i & 1) * 4;
}

// ---------------- features fp32 -> bf16 row-major (halves agg1 gather bytes) ----------------

__global__ __launch_bounds__(256) void feat2bf(const float* __restrict__ x,
                                               ushort* __restrict__ o, int n4) {
    int i = blockIdx.x * 256 + threadIdx.x;
    if (i < n4) {
        float4 v = *(const float4*)&x[(size_t)i * 4];
        *(ushort4*)&o[(size_t)i * 4] = round4(v);
    }
}

// ---------------- agg1: bf16 features -> FRAG bf16 plane ----------------
// one wave per node; lane i holds k 4i..4i+3 (a0) and k 256+4i.. (a1, lanes<27)

__global__ __launch_bounds__(256) void agg1_kernel(
    const ushort* __restrict__ xb, const int* __restrict__ rowptr,
    const int* __restrict__ deg, const int* __restrict__ esrc,
    ushort* __restrict__ of, int nrows) {
    int wid = (blockIdx.x * 256 + threadIdx.x) >> 6;
    if (wid >= nrows) return;
    int lane = threadIdx.x & 63;
    int start = rowptr[wid];
    int d = deg[wid];
    bool hi2 = lane < 27;

    const ushort* xr = xb + (size_t)wid * DF;
    float4 a0 = bf4tof4(*(const ushort4*)&xr[4 * lane]);
    float4 a1 = hi2 ? bf4tof4(*(const ushort4*)&xr[256 + 4 * lane])
                    : make_float4(0.f, 0.f, 0.f, 0.f);

    int j = 0;
    for (; j + 1 < d; j += 2) {
        int s0 = esrc[start + j], s1 = esrc[start + j + 1];
        const ushort* r0 = xb + (size_t)s0 * DF;
        const ushort* r1 = xb + (size_t)s1 * DF;
        ushort4 b0 = *(const ushort4*)&r0[4 * lane];
        ushort4 b1 = *(const ushort4*)&r1[4 * lane];
        f4add(a0, bf4tof4(b0));
        f4add(a0, bf4tof4(b1));
        if (hi2) {
            ushort4 c0 = *(const ushort4*)&r0[256 + 4 * lane];
            ushort4 c1 = *(const ushort4*)&r1[256 + 4 * lane];
            f4add(a1, bf4tof4(c0));
            f4add(a1, bf4tof4(c1));
        }
    }
    if (j < d) {
        int s0 = esrc[start + j];
        const ushort* r0 = xb + (size_t)s0 * DF;
        f4add(a0, bf4tof4(*(const ushort4*)&r0[4 * lane]));
        if (hi2) f4add(a1, bf4tof4(*(const ushort4*)&r0[256 + 4 * lane]));
    }

    int g = wid >> 4, rr = wid & 15;
    *(ushort4*)&of[frag_off_lo(g, rr, lane)] = round4(a0);
    if (lane < 32) {  // k 256..383; lanes 27..31 zero-pad (k >= 364)
        float4 v = hi2 ? a1 : make_float4(0.f, 0.f, 0.f, 0.f);
        *(ushort4*)&of[frag_off_hi(g, rr, lane)] = round4(v);
    }
}

// ---------------- agg2: row-major bf16 h1 -> FRAG bf16, gathered rows ----------------
// one wave per output row; lanes 0..47 each own 8 consecutive k (k = lane*8)

__global__ __launch_bounds__(256) void agg2_kernel(
    const ushort* __restrict__ h1, const int* __restrict__ rowptr,
    const int* __restrict__ deg, const int* __restrict__ esrc,
    const int* __restrict__ v1, const int* __restrict__ v2,
    ushort* __restrict__ of, int nrows) {
    int wid = (blockIdx.x * 256 + threadIdx.x) >> 6;
    if (wid >= nrows) return;
    int lane = threadIdx.x & 63;
    int node = (wid < NP) ? v1[wid] : v2[wid - NP];
    int start = rowptr[node];
    int d = deg[node];
    bool act = lane < 48;  // 48 * 8 = 384 cols

    float f[8] = {};
    if (act) {
        u16x8 v = *(const u16x8*)&h1[(size_t)node * KP + lane * 8];
#pragma unroll
        for (int i = 0; i < 8; ++i) f[i] = bf2f(v[i]);
    }
    for (int j = 0; j < d; ++j) {
        int s = esrc[start + j];
        if (act) {
            u16x8 v = *(const u16x8*)&h1[(size_t)s * KP + lane * 8];
#pragma unroll
            for (int i = 0; i < 8; ++i) f[i] += bf2f(v[i]);
        }
    }
    if (act) {
        u16x8 o;
#pragma unroll
        for (int i = 0; i < 8; ++i) o[i] = f2bf(f[i]);
        int g = wid >> 4, rr = wid & 15;
        size_t off = (size_t)(g * 12 + (lane >> 2)) * 512 + (lane & 3) * 128 + rr * 8;
        *(u16x8*)&of[off] = o;
    }
}

// ---------------- weight prep: W[K][N] fp32 -> FRAG hi/lo planes over (n, k) ----------------

__global__ void prep_w(const float* __restrict__ W, int K, int Nn,
                       ushort* __restrict__ th, ushort* __restrict__ tl) {
    int idx = blockIdx.x * 256 + threadIdx.x;
    if (idx >= KP * KP) return;
    int e = idx & 7;
    int rr = (idx >> 3) & 15;
    int sub = (idx >> 7) & 3;
    int gc = idx >> 9;
    int g = gc / 12, c = gc - g * 12;
    int k = c * 32 + sub * 8 + e;
    int n = g * 16 + rr;
    float v = (k < K && n < Nn) ? W[(size_t)k * Nn + n] : 0.f;
    unsigned short h = f2bf(v);
    th[idx] = h;
    tl[idx] = f2bf(v - bf2f(h));
}

// ---------------- LDS MFMA GEMM (operand-swapped): C'[n][row] = lrelu(W^T @ X^T) ----------------
// A-operand = weights frag hi/lo (rows' = output dim n), B-operand = activations frag
// (cols' = batch row). D rows' = weight dim -> each lane holds 4 CONSECUTIVE rows'
// at fixed col' per (m,n) -> packed 4-element stores everywhere.
// LDS: 2 bufs x 3 planes (Awh, Awl, Bact) x 4096 ushort = 48 KB -> 3 blocks/CU.
// mode 0: C -> h1 row-major bf16:   h1[col'][rbase..rbase+3]       (ushort4)
// mode 1: C -> h2t FRAG bf16 over (n=col', k=row')                 (ushort4)
// mode 2: C -> out fp32 row-major:  out[col'][rbase..rbase+3]      (float2 x2)

__global__ __launch_bounds__(256, 3) void gemm_lds(
    const ushort* __restrict__ Awh, const ushort* __restrict__ Awl,
    const ushort* __restrict__ Bact, const float* __restrict__ bias,
    ushort* __restrict__ Cbf, float* __restrict__ Cf32,
    int Nrow, int mode) {
    __shared__ __align__(16) ushort lds[2][3][4096];  // 48 KB

    int tid = threadIdx.x;
    int lane = tid & 63;
    int wv = tid >> 6;
    int wr = wv >> 1, wc = wv & 1;
    int brow = blockIdx.x * 128, bcol = blockIdx.y * 128;
    int rg = brow >> 4, cg = bcol >> 4;

#define STAGE(buf, tt)                                                                  \
    do {                                                                                \
        _Pragma("unroll") for (int j_ = 0; j_ < 6; ++j_) {                              \
            int g24_ = wv * 6 + j_;                                                     \
            int p_ = g24_ >> 3, gg_ = g24_ & 7;                                         \
            const ushort* base_ = (p_ == 0) ? Awh : ((p_ == 1) ? Awl : Bact);           \
            int grp_ = ((p_ == 2) ? cg : rg) + gg_;                                     \
            const ushort* s_ = base_ + ((size_t)grp_ * 12 + (tt)) * 512 + lane * 8;     \
            __builtin_amdgcn_global_load_lds(                                           \
                (const __attribute__((address_space(1))) unsigned int*)s_,              \
                (__attribute__((address_space(3))) unsigned int*)(&lds[buf][p_][gg_ * 512]), \
                16, 0, 0);                                                              \
        }                                                                               \
    } while (0)

    // fragment read offset within a plane: group*512 + sub*128 + rr*8
    int flo = (lane >> 4) * 128 + (lane & 15) * 8;

    f32x4 acc[4][4];
#pragma unroll
    for (int m = 0; m < 4; ++m)
#pragma unroll
        for (int n = 0; n < 4; ++n) acc[m][n] = (f32x4){0.f, 0.f, 0.f, 0.f};

    STAGE(0, 0);
    __syncthreads();

    for (int t = 0; t < KP / 32; ++t) {
        int cur = t & 1;
        if (t + 1 < KP / 32) STAGE(1 - cur, t + 1);
        bf16x8 ah[4], al[4], b[4];
#pragma unroll
        for (int m = 0; m < 4; ++m) {
            ah[m] = *(const bf16x8*)&lds[cur][0][(wr * 4 + m) * 512 + flo];
            al[m] = *(const bf16x8*)&lds[cur][1][(wr * 4 + m) * 512 + flo];
        }
#pragma unroll
        for (int n = 0; n < 4; ++n)
            b[n] = *(const bf16x8*)&lds[cur][2][(wc * 4 + n) * 512 + flo];
#pragma unroll
        for (int m = 0; m < 4; ++m)
#pragma unroll
            for (int n = 0; n < 4; ++n) {
                mfma16(acc[m][n], ah[m], b[n]);
                mfma16(acc[m][n], al[m], b[n]);
            }
        __syncthreads();
    }
#undef STAGE

    // epilogue: D row' = (lane>>4)*4 + reg (weight dim), col' = lane&15 (batch dim)
    int crow_l = (lane >> 4) * 4;
    int ccol_l = lane & 15;
#pragma unroll
    for (int m = 0; m < 4; ++m) {
        int rb = brow + wr * 64 + m * 16 + crow_l;  // multiple of 4
        float bq[4];
        if (rb + 3 < Nrow) {
            float4 t = *(const float4*)&bias[rb];
            bq[0] = t.x; bq[1] = t.y; bq[2] = t.z; bq[3] = t.w;
        } else {
#pragma unroll
            for (int r = 0; r < 4; ++r) bq[r] = (rb + r < Nrow) ? bias[rb + r] : 0.f;
        }
#pragma unroll
        for (int n = 0; n < 4; ++n) {
            int col = bcol + wc * 64 + n * 16 + ccol_l;
            float v[4];
#pragma unroll
            for (int r = 0; r < 4; ++r) {
                float x = acc[m][n][r] + bq[r];
                v[r] = (x >= 0.f) ? x : NEG_SLOPE * x;
            }
            if (mode == 0) {
                // rows' >= Nrow: weights+bias zero-padded -> v = 0 (needed pad) -> store
                ushort4 h;
                h.x = f2bf(v[0]); h.y = f2bf(v[1]); h.z = f2bf(v[2]); h.w = f2bf(v[3]);
                *(ushort4*)&Cbf[(size_t)col * KP + rb] = h;
            } else if (mode == 1) {
                ushort4 h;
                h.x = f2bf(v[0]); h.y = f2bf(v[1]); h.z = f2bf(v[2]); h.w = f2bf(v[3]);
                size_t off = ((size_t)(col >> 4) * 12 + (rb >> 5)) * 512 +
                             ((rb >> 3) & 3) * 128 + (col & 15) * 8 + (rb & 7);
                *(ushort4*)&Cbf[off] = h;
            } else {
                float* op = Cf32 + (size_t)col * DOUT + rb;
                if (rb + 3 < Nrow) {
                    *(float2*)op = make_float2(v[0], v[1]);
                    *(float2*)(op + 2) = make_float2(v[2], v[3]);
                } else {
#pragma unroll
                    for (int r = 0; r < 4; ++r)
                        if (rb + r < Nrow) op[r] = v[r];
                }
            }
        }
    }
}

// ---------------- row L2 normalize (in place) ----------------

__global__ __launch_bounds__(256) void norm_kernel(float* __restrict__ out, int nrows) {
    int wid = (blockIdx.x * 256 + threadIdx.x) >> 6;
    if (wid >= nrows) return;
    int lane = threadIdx.x & 63;
    float* row = out + (size_t)wid * DOUT;
    float a = row[lane];
    float b = row[lane + 64];
    float cc = (lane + 128 < DOUT) ? row[lane + 128] : 0.f;
    float s = a * a + b * b + cc * cc;
#pragma unroll
    for (int off = 32; off; off >>= 1) s += __shfl_xor(s, off, 64);
    float scale = 1.0f / fmaxf(sqrtf(s), 1e-12f);
    row[lane] = a * scale;
    row[lane + 64] = b * scale;
    if (lane + 128 < DOUT) row[lane + 128] = cc * scale;
}

// ---------------- launch ----------------

extern "C" void kernel_launch(void* const* d_in, const int* in_sizes, int n_in,
                              void* d_out, int out_size, void* d_ws, size_t ws_size,
                              hipStream_t stream) {
    const float* features = (const float*)d_in[0];
    const int* src = (const int*)d_in[1];
    const int* dst = (const int*)d_in[2];
    const int* v1 = (const int*)d_in[3];
    const int* v2 = (const int*)d_in[4];
    const float* W1 = (const float*)d_in[5];
    const float* b1 = (const float*)d_in[6];
    const float* W2 = (const float*)d_in[7];
    const float* b2 = (const float*)d_in[8];
    const float* W3 = (const float*)d_in[9];
    const float* b3 = (const float*)d_in[10];
    float* out = (float*)d_out;

    const int MPAD = 50048;                  // 391 col-tiles of 128
    const size_t PLANE = (size_t)MPAD * KP;  // ushort elems
    const size_t WSZ = (size_t)KP * KP;

    char* p = (char*)d_ws;
    ushort* a1f = (ushort*)p; p += PLANE * 2;   // activations frag (L1 in / L2 in)
    ushort* h1 = (ushort*)p; p += PLANE * 2;    // h1 row-major bf16 / h2t frag
    ushort* fbf = (ushort*)p; p += (size_t)NN * DF * 2;  // bf16 features
    ushort* wt1h = (ushort*)p; p += WSZ * 2;
    ushort* wt1l = (ushort*)p; p += WSZ * 2;
    ushort* wt2h = (ushort*)p; p += WSZ * 2;
    ushort* wt2l = (ushort*)p; p += WSZ * 2;
    ushort* wt3h = (ushort*)p; p += WSZ * 2;
    ushort* wt3l = (ushort*)p; p += WSZ * 2;
    int* deg = (int*)p; p += NN * 4;
    int* rowptr = (int*)p; p += NN * 4;
    int* pos = (int*)p; p += NN * 4;
    int* esrc = (int*)p; p += NE * 4;
    int* bsum = (int*)p; p += 256;
    ushort* a2f = a1f;  // layer-2 agg out (frag, 16384 rows)
    ushort* h2t = h1;   // layer-2 gemm out (transposed frag)

    const int NSB = (NN + 1023) / 1024;

    hipMemsetAsync(deg, 0, NN * sizeof(int), stream);
    hist_kernel<<<(NE + 255) / 256, 256, 0, stream>>>(dst, deg, NE);
    scan_block<<<NSB, 1024, 0, stream>>>(deg, rowptr, bsum, NN);
    scan_small<<<1, 64, 0, stream>>>(bsum, NSB);
    add_off<<<NSB, 1024, 0, stream>>>(rowptr, bsum, pos, NN);
    fill_kernel<<<(NE + 255) / 256, 256, 0, stream>>>(src, dst, pos, esrc, NE);

    feat2bf<<<(NN * DF / 4 + 255) / 256, 256, 0, stream>>>(features, fbf, NN * DF / 4);
    prep_w<<<(KP * KP + 255) / 256, 256, 0, stream>>>(W1, DF, DF, wt1h, wt1l);
    prep_w<<<(KP * KP + 255) / 256, 256, 0, stream>>>(W2, DF, DF, wt2h, wt2l);
    prep_w<<<(KP * KP + 255) / 256, 256, 0, stream>>>(W3, DF, DOUT, wt3h, wt3l);

    // layer 1 (all nodes): agg -> a1f frag; gemm': A=W1^T-frag, B=a1f -> h1 row-major
    agg1_kernel<<<(NN * 64 + 255) / 256, 256, 0, stream>>>(fbf, rowptr, deg, esrc,
                                                           a1f, NN);
    gemm_lds<<<dim3(3, 391), 256, 0, stream>>>(wt1h, wt1l, a1f, b1,
                                               h1, nullptr, DF, 0);

    // layer 2 (16384 gathered rows): h1 -> a2f frag; gemm' -> h2t frag (n=16384, k=384)
    const int NR = 2 * NP;
    agg2_kernel<<<(NR * 64 + 255) / 256, 256, 0, stream>>>(h1, rowptr, deg, esrc,
                                                           v1, v2, a2f, NR);
    gemm_lds<<<dim3(3, 128), 256, 0, stream>>>(wt2h, wt2l, a2f, b2,
                                               h2t, nullptr, DF, 1);

    // projection: A=W3^T-frag, B=h2t -> out fp32 [16384][150], then normalize
    gemm_lds<<<dim3(2, 128), 256, 0, stream>>>(wt3h, wt3l, h2t, b3,
                                               nullptr, out, DOUT, 2);
    norm_kernel<<<(NR * 64 + 255) / 256, 256, 0, stream>>>(out, NR);
}

// Round 11
// 289.406 us; speedup vs baseline: 1.6405x; 1.0461x over previous
//
#include <hip/hip_runtime.h>

#define NN 50000     // nodes
#define NE 200000    // edges
#define DF 364       // feature dim
#define KP 384       // padded K (12 x 32)
#define DOUT 150     // output dim
#define NP 8192      // pairs
#define NEG_SLOPE 0.01f

typedef float f32x4 __attribute__((ext_vector_type(4)));
typedef short bf16x8 __attribute__((ext_vector_type(8)));
typedef unsigned short u16x8 __attribute__((ext_vector_type(8)));

__device__ __forceinline__ unsigned short f2bf(float x) {
    unsigned u = __float_as_uint(x);
    u += 0x7FFF + ((u >> 16) & 1);  // RN-even; inputs finite
    return (unsigned short)(u >> 16);
}
__device__ __forceinline__ float bf2f(unsigned short h) {
    return __uint_as_float(((unsigned)h) << 16);
}

__device__ __forceinline__ void mfma16(f32x4& d, bf16x8 a, bf16x8 b) {
    d = __builtin_amdgcn_mfma_f32_16x16x32_bf16(a, b, d, 0, 0, 0);
}

// FRAG layout (hardware-validated rounds 6/9/10): for (idx, k):
//   g=idx>>4, rr=idx&15, c=k>>5, sub=(k>>3)&3, e=k&7
//   flat = (g*12 + c)*512 + sub*128 + rr*8 + e

// ---------------- CSR build ----------------

__global__ __launch_bounds__(1024) void scan_block(const int* __restrict__ deg,
                                                   int* __restrict__ rowptr,
                                                   int* __restrict__ bsum, int n) {
    __shared__ int lds[1024];
    int b = blockIdx.x, t = threadIdx.x;
    int i = b * 1024 + t;
    int v = (i < n) ? deg[i] : 0;
    lds[t] = v;
    __syncthreads();
    for (int off = 1; off < 1024; off <<= 1) {
        int x = (t >= off) ? lds[t - off] : 0;
        __syncthreads();
        lds[t] += x;
        __syncthreads();
    }
    if (i < n) rowptr[i] = lds[t] - v;
    if (t == 1023) bsum[b] = lds[1023];
}

__global__ void scan_small(int* __restrict__ bsum, int nb) {
    int t = threadIdx.x;
    int orig = (t < nb) ? bsum[t] : 0;
    int v = orig;
#pragma unroll
    for (int off = 1; off < 64; off <<= 1) {
        int u = __shfl_up(v, off, 64);
        if (t >= off) v += u;
    }
    if (t < nb) bsum[t] = v - orig;
}

__global__ __launch_bounds__(1024) void add_off(int* __restrict__ rowptr,
                                                const int* __restrict__ bsum,
                                                int* __restrict__ pos, int n) {
    int i = blockIdx.x * 1024 + threadIdx.x;
    if (i < n) {
        int v = rowptr[i] + bsum[blockIdx.x];
        rowptr[i] = v;
        pos[i] = v;
    }
}

__global__ void fill_kernel(const int* __restrict__ src, const int* __restrict__ dst,
                            int* __restrict__ pos, int* __restrict__ esrc, int n) {
    int t = blockIdx.x * blockDim.x + threadIdx.x;
    if (t < n) {
        int j = atomicAdd(&pos[dst[t]], 1);
        esrc[j] = src[t];
    }
}

// ---------------- helpers ----------------

__device__ __forceinline__ ushort4 round4(float4 v) {
    ushort4 h;
    h.x = f2bf(v.x); h.y = f2bf(v.y); h.z = f2bf(v.z); h.w = f2bf(v.w);
    return h;
}

__device__ __forceinline__ float4 bf4tof4(ushort4 u) {
    return make_float4(bf2f(u.x), bf2f(u.y), bf2f(u.z), bf2f(u.w));
}

__device__ __forceinline__ void f4add(float4& a, const float4 b) {
    a.x += b.x; a.y += b.y; a.z += b.z; a.w += b.w;
}

// frag ushort4 store offset for lane-chunk i, LOW 256 k (k0 = 4i), i in 0..63
__device__ __forceinline__ size_t frag_off_lo(int g, int rr, int i) {
    return (size_t)(g * 12 + (i >> 3)) * 512 + ((i >> 1) & 3) * 128 + rr * 8 + (i & 1) * 4;
}
// HIGH 128 k (k0 = 256 + 4i), i in 0..31
__device__ __forceinline__ size_t frag_off_hi(int g, int rr, int i) {
    return (size_t)(g * 12 + 8 + (i >> 3)) * 512 + ((i >> 1) & 3) * 128 + rr * 8 + (i & 1) * 4;
}

// ---------------- fused prep: feat->bf16, W1/W2 frag bf16, W3 frag hi+lo, degree hist ----
// All parts independent -> one dispatch, concurrent blocks.

#define NBF 17774            // ceil(NN*DF/4 / 256)
#define NW 576               // ceil(KP*KP / 256)
#define NH 782               // ceil(NE / 256)

__device__ __forceinline__ void prep_w_one(const float* __restrict__ W, int K, int Nn,
                                           ushort* __restrict__ th, ushort* __restrict__ tl,
                                           int idx) {
    if (idx >= KP * KP) return;
    int e = idx & 7;
    int rr = (idx >> 3) & 15;
    int sub = (idx >> 7) & 3;
    int gc = idx >> 9;
    int g = gc / 12, c = gc - g * 12;
    int k = c * 32 + sub * 8 + e;
    int n = g * 16 + rr;
    float v = (k < K && n < Nn) ? W[(size_t)k * Nn + n] : 0.f;
    unsigned short h = f2bf(v);
    th[idx] = h;
    if (tl) tl[idx] = f2bf(v - bf2f(h));
}

__global__ __launch_bounds__(256) void prep_all(
    const float* __restrict__ features, ushort* __restrict__ fbf,
    const float* __restrict__ W1, ushort* __restrict__ wt1,
    const float* __restrict__ W2, ushort* __restrict__ wt2,
    const float* __restrict__ W3, ushort* __restrict__ wt3h, ushort* __restrict__ wt3l,
    const int* __restrict__ dst, int* __restrict__ deg) {
    int b = blockIdx.x, tid = threadIdx.x;
    if (b < NBF) {
        int i = b * 256 + tid;
        if (i < NN * DF / 4) {
            float4 v = *(const float4*)&features[(size_t)i * 4];
            *(ushort4*)&fbf[(size_t)i * 4] = round4(v);
        }
    } else if (b < NBF + NW) {
        prep_w_one(W1, DF, DF, wt1, nullptr, (b - NBF) * 256 + tid);
    } else if (b < NBF + 2 * NW) {
        prep_w_one(W2, DF, DF, wt2, nullptr, (b - NBF - NW) * 256 + tid);
    } else if (b < NBF + 3 * NW) {
        prep_w_one(W3, DF, DOUT, wt3h, wt3l, (b - NBF - 2 * NW) * 256 + tid);
    } else {
        int t = (b - NBF - 3 * NW) * 256 + tid;
        if (t < NE) atomicAdd(&deg[dst[t]], 1);
    }
}

// ---------------- agg1: bf16 features -> FRAG bf16 plane ----------------

__global__ __launch_bounds__(256) void agg1_kernel(
    const ushort* __restrict__ xb, const int* __restrict__ rowptr,
    const int* __restrict__ deg, const int* __restrict__ esrc,
    ushort* __restrict__ of, int nrows) {
    int wid = (blockIdx.x * 256 + threadIdx.x) >> 6;
    if (wid >= nrows) return;
    int lane = threadIdx.x & 63;
    int start = rowptr[wid];
    int d = deg[wid];
    bool hi2 = lane < 27;

    const ushort* xr = xb + (size_t)wid * DF;
    float4 a0 = bf4tof4(*(const ushort4*)&xr[4 * lane]);
    float4 a1 = hi2 ? bf4tof4(*(const ushort4*)&xr[256 + 4 * lane])
                    : make_float4(0.f, 0.f, 0.f, 0.f);

    int j = 0;
    for (; j + 1 < d; j += 2) {
        int s0 = esrc[start + j], s1 = esrc[start + j + 1];
        const ushort* r0 = xb + (size_t)s0 * DF;
        const ushort* r1 = xb + (size_t)s1 * DF;
        ushort4 b0 = *(const ushort4*)&r0[4 * lane];
        ushort4 b1 = *(const ushort4*)&r1[4 * lane];
        f4add(a0, bf4tof4(b0));
        f4add(a0, bf4tof4(b1));
        if (hi2) {
            ushort4 c0 = *(const ushort4*)&r0[256 + 4 * lane];
            ushort4 c1 = *(const ushort4*)&r1[256 + 4 * lane];
            f4add(a1, bf4tof4(c0));
            f4add(a1, bf4tof4(c1));
        }
    }
    if (j < d) {
        int s0 = esrc[start + j];
        const ushort* r0 = xb + (size_t)s0 * DF;
        f4add(a0, bf4tof4(*(const ushort4*)&r0[4 * lane]));
        if (hi2) f4add(a1, bf4tof4(*(const ushort4*)&r0[256 + 4 * lane]));
    }

    int g = wid >> 4, rr = wid & 15;
    *(ushort4*)&of[frag_off_lo(g, rr, lane)] = round4(a0);
    if (lane < 32) {  // k 256..383; lanes 27..31 zero-pad (k >= 364)
        float4 v = hi2 ? a1 : make_float4(0.f, 0.f, 0.f, 0.f);
        *(ushort4*)&of[frag_off_hi(g, rr, lane)] = round4(v);
    }
}

// ---------------- agg2: row-major bf16 h1 -> FRAG bf16, gathered rows ----------------

__global__ __launch_bounds__(256) void agg2_kernel(
    const ushort* __restrict__ h1, const int* __restrict__ rowptr,
    const int* __restrict__ deg, const int* __restrict__ esrc,
    const int* __restrict__ v1, const int* __restrict__ v2,
    ushort* __restrict__ of, int nrows) {
    int wid = (blockIdx.x * 256 + threadIdx.x) >> 6;
    if (wid >= nrows) return;
    int lane = threadIdx.x & 63;
    int node = (wid < NP) ? v1[wid] : v2[wid - NP];
    int start = rowptr[node];
    int d = deg[node];
    bool act = lane < 48;  // 48 * 8 = 384 cols

    float f[8] = {};
    if (act) {
        u16x8 v = *(const u16x8*)&h1[(size_t)node * KP + lane * 8];
#pragma unroll
        for (int i = 0; i < 8; ++i) f[i] = bf2f(v[i]);
    }
    for (int j = 0; j < d; ++j) {
        int s = esrc[start + j];
        if (act) {
            u16x8 v = *(const u16x8*)&h1[(size_t)s * KP + lane * 8];
#pragma unroll
            for (int i = 0; i < 8; ++i) f[i] += bf2f(v[i]);
        }
    }
    if (act) {
        u16x8 o;
#pragma unroll
        for (int i = 0; i < 8; ++i) o[i] = f2bf(f[i]);
        int g = wid >> 4, rr = wid & 15;
        size_t off = (size_t)(g * 12 + (lane >> 2)) * 512 + (lane & 3) * 128 + rr * 8;
        *(u16x8*)&of[off] = o;
    }
}

// ---------------- LDS MFMA GEMM (operand-swapped), WP weight planes ----------------
// A-operand = weights frag (WP planes: hi [+ lo]), B-operand = activations frag.
// WP=1: LDS 32 KB -> 5 blocks/CU, 16 MFMA/K-step. WP=2: 48 KB -> 3 blocks/CU, 32 MFMA.
// mode 0: C -> h1 row-major bf16 [col][rb]   mode 1: C -> FRAG bf16 (n=col,k=rb)
// mode 2: C -> fp32 row-major out[col][rb]

template <int WP>
__global__ __launch_bounds__(256, 3) void gemm_lds(
    const ushort* __restrict__ Awh, const ushort* __restrict__ Awl,
    const ushort* __restrict__ Bact, const float* __restrict__ bias,
    ushort* __restrict__ Cbf, float* __restrict__ Cf32,
    int Nrow, int mode) {
    constexpr int PL = WP + 1;           // total LDS planes (weights + activations)
    __shared__ __align__(16) ushort lds[2][PL][4096];

    int tid = threadIdx.x;
    int lane = tid & 63;
    int wv = tid >> 6;
    int wr = wv >> 1, wc = wv & 1;
    int brow = blockIdx.x * 128, bcol = blockIdx.y * 128;
    int rg = brow >> 4, cg = bcol >> 4;

#define STAGE(buf, tt)                                                                  \
    do {                                                                                \
        _Pragma("unroll") for (int j_ = 0; j_ < 2 * PL; ++j_) {                         \
            int g24_ = wv * 2 * PL + j_;                                                \
            int p_ = g24_ >> 3, gg_ = g24_ & 7;                                         \
            const ushort* base_ = (p_ == 0) ? Awh : ((WP == 2 && p_ == 1) ? Awl : Bact);\
            int grp_ = ((p_ == WP) ? cg : rg) + gg_;                                    \
            const ushort* s_ = base_ + ((size_t)grp_ * 12 + (tt)) * 512 + lane * 8;     \
            __builtin_amdgcn_global_load_lds(                                           \
                (const __attribute__((address_space(1))) unsigned int*)s_,              \
                (__attribute__((address_space(3))) unsigned int*)(&lds[buf][p_][gg_ * 512]), \
                16, 0, 0);                                                              \
        }                                                                               \
    } while (0)

    int flo = (lane >> 4) * 128 + (lane & 15) * 8;

    f32x4 acc[4][4];
#pragma unroll
    for (int m = 0; m < 4; ++m)
#pragma unroll
        for (int n = 0; n < 4; ++n) acc[m][n] = (f32x4){0.f, 0.f, 0.f, 0.f};

    STAGE(0, 0);
    __syncthreads();

    for (int t = 0; t < KP / 32; ++t) {
        int cur = t & 1;
        if (t + 1 < KP / 32) STAGE(1 - cur, t + 1);
        bf16x8 ah[4], al[4], b[4];
#pragma unroll
        for (int m = 0; m < 4; ++m) {
            ah[m] = *(const bf16x8*)&lds[cur][0][(wr * 4 + m) * 512 + flo];
            if (WP == 2) al[m] = *(const bf16x8*)&lds[cur][1][(wr * 4 + m) * 512 + flo];
        }
#pragma unroll
        for (int n = 0; n < 4; ++n)
            b[n] = *(const bf16x8*)&lds[cur][WP][(wc * 4 + n) * 512 + flo];
#pragma unroll
        for (int m = 0; m < 4; ++m)
#pragma unroll
            for (int n = 0; n < 4; ++n) {
                mfma16(acc[m][n], ah[m], b[n]);
                if (WP == 2) mfma16(acc[m][n], al[m], b[n]);
            }
        __syncthreads();
    }
#undef STAGE

    // epilogue: D row' = (lane>>4)*4 + reg (weight dim), col' = lane&15 (batch dim)
    int crow_l = (lane >> 4) * 4;
    int ccol_l = lane & 15;
#pragma unroll
    for (int m = 0; m < 4; ++m) {
        int rb = brow + wr * 64 + m * 16 + crow_l;  // multiple of 4
        float bq[4];
        if (rb + 3 < Nrow) {
            float4 t = *(const float4*)&bias[rb];
            bq[0] = t.x; bq[1] = t.y; bq[2] = t.z; bq[3] = t.w;
        } else {
#pragma unroll
            for (int r = 0; r < 4; ++r) bq[r] = (rb + r < Nrow) ? bias[rb + r] : 0.f;
        }
#pragma unroll
        for (int n = 0; n < 4; ++n) {
            int col = bcol + wc * 64 + n * 16 + ccol_l;
            float v[4];
#pragma unroll
            for (int r = 0; r < 4; ++r) {
                float x = acc[m][n][r] + bq[r];
                v[r] = (x >= 0.f) ? x : NEG_SLOPE * x;
            }
            if (mode == 0) {
                ushort4 h;
                h.x = f2bf(v[0]); h.y = f2bf(v[1]); h.z = f2bf(v[2]); h.w = f2bf(v[3]);
                *(ushort4*)&Cbf[(size_t)col * KP + rb] = h;
            } else if (mode == 1) {
                ushort4 h;
                h.x = f2bf(v[0]); h.y = f2bf(v[1]); h.z = f2bf(v[2]); h.w = f2bf(v[3]);
                size_t off = ((size_t)(col >> 4) * 12 + (rb >> 5)) * 512 +
                             ((rb >> 3) & 3) * 128 + (col & 15) * 8 + (rb & 7);
                *(ushort4*)&Cbf[off] = h;
            } else {
                float* op = Cf32 + (size_t)col * DOUT + rb;
                if (rb + 3 < Nrow) {
                    *(float2*)op = make_float2(v[0], v[1]);
                    *(float2*)(op + 2) = make_float2(v[2], v[3]);
                } else {
#pragma unroll
                    for (int r = 0; r < 4; ++r)
                        if (rb + r < Nrow) op[r] = v[r];
                }
            }
        }
    }
}

// ---------------- row L2 normalize (in place) ----------------

__global__ __launch_bounds__(256) void norm_kernel(float* __restrict__ out, int nrows) {
    int wid = (blockIdx.x * 256 + threadIdx.x) >> 6;
    if (wid >= nrows) return;
    int lane = threadIdx.x & 63;
    float* row = out + (size_t)wid * DOUT;
    float a = row[lane];
    float b = row[lane + 64];
    float cc = (lane + 128 < DOUT) ? row[lane + 128] : 0.f;
    float s = a * a + b * b + cc * cc;
#pragma unroll
    for (int off = 32; off; off >>= 1) s += __shfl_xor(s, off, 64);
    float scale = 1.0f / fmaxf(sqrtf(s), 1e-12f);
    row[lane] = a * scale;
    row[lane + 64] = b * scale;
    if (lane + 128 < DOUT) row[lane + 128] = cc * scale;
}

// ---------------- launch ----------------

extern "C" void kernel_launch(void* const* d_in, const int* in_sizes, int n_in,
                              void* d_out, int out_size, void* d_ws, size_t ws_size,
                              hipStream_t stream) {
    const float* features = (const float*)d_in[0];
    const int* src = (const int*)d_in[1];
    const int* dst = (const int*)d_in[2];
    const int* v1 = (const int*)d_in[3];
    const int* v2 = (const int*)d_in[4];
    const float* W1 = (const float*)d_in[5];
    const float* b1 = (const float*)d_in[6];
    const float* W2 = (const float*)d_in[7];
    const float* b2 = (const float*)d_in[8];
    const float* W3 = (const float*)d_in[9];
    const float* b3 = (const float*)d_in[10];
    float* out = (float*)d_out;

    const int MPAD = 50048;                  // 391 col-tiles of 128
    const size_t PLANE = (size_t)MPAD * KP;  // ushort elems
    const size_t WSZ = (size_t)KP * KP;

    char* p = (char*)d_ws;
    ushort* a1f = (ushort*)p; p += PLANE * 2;   // activations frag (L1 in / L2 in)
    ushort* h1 = (ushort*)p; p += PLANE * 2;    // h1 row-major bf16 / h2t frag
    ushort* fbf = (ushort*)p; p += (size_t)NN * DF * 2;  // bf16 features
    ushort* wt1 = (ushort*)p; p += WSZ * 2;     // W1 frag bf16 (single plane)
    ushort* wt2 = (ushort*)p; p += WSZ * 2;     // W2 frag bf16 (single plane)
    ushort* wt3h = (ushort*)p; p += WSZ * 2;    // W3 frag hi
    ushort* wt3l = (ushort*)p; p += WSZ * 2;    // W3 frag lo
    int* deg = (int*)p; p += NN * 4;
    int* rowptr = (int*)p; p += NN * 4;
    int* pos = (int*)p; p += NN * 4;
    int* esrc = (int*)p; p += NE * 4;
    int* bsum = (int*)p; p += 256;
    ushort* a2f = a1f;  // layer-2 agg out (frag, 16384 rows)
    ushort* h2t = h1;   // layer-2 gemm out (frag)

    const int NSB = (NN + 1023) / 1024;

    hipMemsetAsync(deg, 0, NN * sizeof(int), stream);
    // fused: feat->bf16 | W1,W2 frag | W3 frag hi+lo | degree histogram
    prep_all<<<NBF + 3 * NW + NH, 256, 0, stream>>>(features, fbf, W1, wt1, W2, wt2,
                                                    W3, wt3h, wt3l, dst, deg);
    scan_block<<<NSB, 1024, 0, stream>>>(deg, rowptr, bsum, NN);
    scan_small<<<1, 64, 0, stream>>>(bsum, NSB);
    add_off<<<NSB, 1024, 0, stream>>>(rowptr, bsum, pos, NN);
    fill_kernel<<<(NE + 255) / 256, 256, 0, stream>>>(src, dst, pos, esrc, NE);

    // layer 1 (all nodes): agg -> a1f frag; gemm: A=W1-frag, B=a1f -> h1 row-major
    agg1_kernel<<<(NN * 64 + 255) / 256, 256, 0, stream>>>(fbf, rowptr, deg, esrc,
                                                           a1f, NN);
    gemm_lds<1><<<dim3(3, 391), 256, 0, stream>>>(wt1, nullptr, a1f, b1,
                                                  h1, nullptr, DF, 0);

    // layer 2 (16384 gathered rows): h1 -> a2f frag; gemm -> h2t frag
    const int NR = 2 * NP;
    agg2_kernel<<<(NR * 64 + 255) / 256, 256, 0, stream>>>(h1, rowptr, deg, esrc,
                                                           v1, v2, a2f, NR);
    gemm_lds<1><<<dim3(3, 128), 256, 0, stream>>>(wt2, nullptr, a2f, b2,
                                                  h2t, nullptr, DF, 1);

    // projection (W3 split hi+lo): -> out fp32 [16384][150], then normalize
    gemm_lds<2><<<dim3(2, 128), 256, 0, stream>>>(wt3h, wt3l, h2t, b3,
                                                  nullptr, out, DOUT, 2);
    norm_kernel<<<(NR * 64 + 255) / 256, 256, 0, stream>>>(out, NR);
}